// Round 2
// baseline (1885.616 us; speedup 1.0000x reference)
//
#include <hip/hip_runtime.h>

typedef unsigned short u16;
typedef __attribute__((ext_vector_type(4))) float f32x4;
typedef __attribute__((ext_vector_type(8))) short s16x8;

constexpr int N = 16, L = 2048, C = 1024, A = 1024;
constexpr int NL = N * L;

__device__ __forceinline__ u16 f2bf(float v) {
  unsigned u = __float_as_uint(v);
  return (u16)((u + 0x7FFFu + ((u >> 16) & 1u)) >> 16);
}
__device__ __forceinline__ float bf2f(u16 h) { return __uint_as_float(((unsigned)h) << 16); }
__device__ __forceinline__ void split1(float v, u16 &h, u16 &l) {
  h = f2bf(v);
  l = f2bf(v - bf2f(h));
}

__device__ __forceinline__ void gload16(const void* g, const void* l) {
  __builtin_amdgcn_global_load_lds((const __attribute__((address_space(1))) void*)g,
                                   (__attribute__((address_space(3))) void*)l, 16, 0, 0);
}

// Data (r, 16B-group g) of a [256][32] bf16 tile, stored as LDS [128][64] with
// XOR swizzle: slot s8' = (((r&1)<<2)|g) ^ ((r>>1)&7). 128B LDS rows => bank
// quad = slot => any 16-row column read is 2-way max (free). Returns elem offset.
__device__ __forceinline__ int lofs2(int r, int g) {
  int R = r >> 1;
  int s = ((((r & 1) << 2) | g) ^ (R & 7));
  return R * 64 + s * 8;
}

// ---------------------------------------------------------------- split W
__global__ __launch_bounds__(256) void split_w(const float* __restrict__ Wk,
                                               const float* __restrict__ Wq,
                                               u16* __restrict__ Whi,
                                               u16* __restrict__ Wlo) {
  int i = (blockIdx.x * 256 + threadIdx.x) * 4;
  if (i >= A * C) return;
  float4 k = *(const float4*)&Wk[i];
  float4 q = *(const float4*)&Wq[i];
  ushort4 h, l;
  split1(k.x, h.x, l.x); split1(k.y, h.y, l.y); split1(k.z, h.z, l.z); split1(k.w, h.w, l.w);
  *(ushort4*)&Whi[i] = h; *(ushort4*)&Wlo[i] = l;
  split1(q.x, h.x, l.x); split1(q.y, h.y, l.y); split1(q.z, h.z, l.z); split1(q.w, h.w, l.w);
  *(ushort4*)&Whi[A * C + i] = h; *(ushort4*)&Wlo[A * C + i] = l;
}

// ---------------------------------------------------------------- split x
__global__ __launch_bounds__(256) void split_x(const float* __restrict__ x,
                                               u16* __restrict__ xh,
                                               u16* __restrict__ xl) {
  size_t i = ((size_t)blockIdx.x * 256 + threadIdx.x) * 4;
  float4 v = *(const float4*)&x[i];
  ushort4 h, l;
  split1(v.x, h.x, l.x); split1(v.y, h.y, l.y); split1(v.z, h.z, l.z); split1(v.w, h.w, l.w);
  *(ushort4*)&xh[i] = h;
  *(ushort4*)&xl[i] = l;
}

// ------------------------------------------------------------- transpose x
// x [N][L][C] fp32 -> xT [N][C][L] bf16
__global__ __launch_bounds__(256) void transpose_x(const float* __restrict__ x,
                                                   u16* __restrict__ xT) {
  __shared__ u16 tile[64 * 68];
  const int n = blockIdx.z;
  const int l0 = blockIdx.x * 64;
  const int c0 = blockIdx.y * 64;
  const int t = threadIdx.x;
  const int cg = t & 15, r = t >> 4;
#pragma unroll
  for (int i = 0; i < 4; ++i) {
    int rr = r + i * 16;
    float4 v = *(const float4*)&x[((size_t)n * L + l0 + rr) * C + c0 + cg * 4];
    ushort4 h;
    h.x = f2bf(v.x); h.y = f2bf(v.y); h.z = f2bf(v.z); h.w = f2bf(v.w);
    *(ushort4*)&tile[rr * 68 + cg * 4] = h;
  }
  __syncthreads();
  const int l4 = (t & 15) * 4;
#pragma unroll
  for (int i = 0; i < 4; ++i) {
    int cc = (t >> 4) + i * 16;
    ushort4 o;
    o.x = tile[(l4 + 0) * 68 + cc];
    o.y = tile[(l4 + 1) * 68 + cc];
    o.z = tile[(l4 + 2) * 68 + cc];
    o.w = tile[(l4 + 3) * 68 + cc];
    *(ushort4*)&xT[((size_t)n * C + c0 + cc) * L + l0 + l4] = o;
  }
}

// ------------------------------------------------- unified 256x256 GEMM
// MODE 0 (KQ):     O[nl][j] = sum_c x[nl][c]*W[j][c], j=(which,a). K'=3C via
//                  segments (xh*Wh + xh*Wl + xl*Wh). Out: bf16 hi/lo.
// MODE 1 (SCORES): S[l][m] = sum_a K[l][a]*Q[m][a], segments Kh*Qh+Kh*Ql+Kl*Qh.
//                  Out: fp32.
// MODE 2 (OUT):    out[l][c] = sum_m attn[l][m]*xT[c][m]. Plain bf16, K=L.
// Depth-4 pipeline: 4 LDS buffers, stage tile t+3 during compute of t,
// counted vmcnt(8) + raw barrier per tile (no drain in steady state).
template <int MODE>
__global__ __launch_bounds__(512, 2) void gemm8(
    const u16* __restrict__ A0, const u16* __restrict__ A1,
    const u16* __restrict__ B0, const u16* __restrict__ B1,
    u16* __restrict__ Oh, u16* __restrict__ Ol, float* __restrict__ Of, int n0) {
  constexpr int NT = (MODE == 2) ? 64 : 96;       // K-tiles of 32
  constexpr int SA = (MODE == 2) ? 4096 : 2048;   // A row stride (bytes)
  constexpr int SB = (MODE == 2) ? 4096 : 2048;
  constexpr int GXL = (MODE == 2) ? 2 : 3;        // log2 gridDim.x
  __shared__ u16 lds[4 * 16384];

  // chunked XCD swizzle (bijective: nwg always a multiple of 8 here)
  const int nwg = gridDim.x * gridDim.y * gridDim.z;
  int lin = ((int)blockIdx.z * gridDim.y + blockIdx.y) * gridDim.x + blockIdx.x;
  int swz = (lin & 7) * (nwg >> 3) + (lin >> 3);
  const int bx = swz & ((1 << GXL) - 1);
  int rem = swz >> GXL;
  const int by = (MODE == 0) ? (rem & 127) : (rem & 7);
  const int bz = (MODE == 0) ? 0 : (rem >> 3);

  const int zn = bz;
  const int row0 = by * 256;
  const int col0 = bx * 256;
  const char *aB0, *aB1 = nullptr, *bB0, *bB1 = nullptr;
  if constexpr (MODE == 0) {
    aB0 = (const char*)(A0 + (size_t)row0 * C);
    aB1 = (const char*)(A1 + (size_t)row0 * C);
    const int which = col0 >> 10, ac = col0 & 1023;
    bB0 = (const char*)(B0 + ((size_t)which * A + ac) * C);
    bB1 = (const char*)(B1 + ((size_t)which * A + ac) * C);
  } else if constexpr (MODE == 1) {
    const int n = n0 + zn;
    aB0 = (const char*)(A0 + ((size_t)n * L + row0) * A);
    aB1 = (const char*)(A1 + ((size_t)n * L + row0) * A);
    bB0 = (const char*)(B0 + ((size_t)n * L + col0) * A);
    bB1 = (const char*)(B1 + ((size_t)n * L + col0) * A);
  } else {
    const int n = n0 + zn;
    aB0 = (const char*)(A0 + ((size_t)zn * L + row0) * L);
    bB0 = (const char*)(B0 + ((size_t)n * C + col0) * L);
  }

  const int t = threadIdx.x;
  const int lane = t & 63, w = t >> 6;
  const int wr = w >> 2, wc = w & 3;
  const int lr = lane & 15, lk = lane >> 4;

  // staging precompute: per wave 2 A-instrs + 2 B-instrs, each covers 8 LDS
  // rows (=16 data rows). Linear LDS dest; inverse-swizzled global source.
  int srcA[2], srcB[2], dstA[2];
#pragma unroll
  for (int i = 0; i < 2; ++i) {
    const int R = w * 16 + i * 8 + (lane >> 3);
    const int s8 = (lane & 7) ^ (R & 7);
    const int r = (R << 1) | (s8 >> 2);
    const int g = s8 & 3;
    srcA[i] = r * SA + g * 16;
    srcB[i] = r * SB + g * 16;
    dstA[i] = (w * 16 + i * 8) * 64 + lane * 8;
  }

  auto stage = [&](int kt) {
    const char *aB, *bB;
    int coff;
    if constexpr (MODE == 2) {
      aB = aB0; bB = bB0; coff = kt * 64;
    } else {
      const int seg = kt >> 5;
      aB = (seg == 2) ? aB1 : aB0;
      bB = (seg == 1) ? bB1 : bB0;
      coff = (kt & 31) * 64;
    }
    u16* buf = &lds[(kt & 3) * 16384];
    gload16(aB + coff + srcA[0], buf + dstA[0]);
    gload16(aB + coff + srcA[1], buf + dstA[1]);
    gload16(bB + coff + srcB[0], buf + dstA[0] + 8192);
    gload16(bB + coff + srcB[1], buf + dstA[1] + 8192);
  };

  f32x4 acc[8][4] = {};
  stage(0); stage(1); stage(2);
  asm volatile("s_waitcnt vmcnt(8)" ::: "memory");
  __builtin_amdgcn_s_barrier();
  for (int kt = 0; kt < NT; ++kt) {
    asm volatile("" ::: "memory");
    if (kt + 3 < NT) stage(kt + 3);
    const u16* bufA = &lds[(kt & 3) * 16384];
    const u16* bufB = bufA + 8192;
    s16x8 bf[4];
#pragma unroll
    for (int ni = 0; ni < 4; ++ni)
      bf[ni] = *(const s16x8*)&bufB[lofs2(wc * 64 + ni * 16 + lr, lk)];
    __builtin_amdgcn_s_setprio(1);
#pragma unroll
    for (int mi = 0; mi < 8; ++mi) {
      s16x8 af = *(const s16x8*)&bufA[lofs2(wr * 128 + mi * 16 + lr, lk)];
#pragma unroll
      for (int ni = 0; ni < 4; ++ni)
        acc[mi][ni] = __builtin_amdgcn_mfma_f32_16x16x32_bf16(af, bf[ni], acc[mi][ni], 0, 0, 0);
    }
    __builtin_amdgcn_s_setprio(0);
    if (kt < NT - 3)        asm volatile("s_waitcnt vmcnt(8)" ::: "memory");
    else if (kt == NT - 3)  asm volatile("s_waitcnt vmcnt(4)" ::: "memory");
    else if (kt == NT - 2)  asm volatile("s_waitcnt vmcnt(0)" ::: "memory");
    __builtin_amdgcn_s_barrier();
  }

#pragma unroll
  for (int mi = 0; mi < 8; ++mi)
#pragma unroll
    for (int ni = 0; ni < 4; ++ni) {
      const int r = row0 + wr * 128 + mi * 16 + lk * 4;
      const int c = wc * 64 + ni * 16 + lr;
#pragma unroll
      for (int j = 0; j < 4; ++j) {
        const float v = acc[mi][ni][j];
        if constexpr (MODE == 0) {
          const int which = col0 >> 10;
          const int ac = (col0 & 1023) + c;
          u16 h, l;
          split1(v, h, l);
          Oh[((size_t)which * NL + r + j) * A + ac] = h;
          Ol[((size_t)which * NL + r + j) * A + ac] = l;
        } else if constexpr (MODE == 1) {
          Of[((size_t)zn * L + r + j) * L + col0 + c] = v;
        } else {
          Of[((size_t)(n0 + zn) * L + r + j) * C + col0 + c] = v;
        }
      }
    }
}

// --------------------------------------------------- column softmax stats
__global__ __launch_bounds__(256) void stats_partial(const float* __restrict__ scores,
                                                     float2* __restrict__ pstats,
                                                     int n0) {
  const int zn = blockIdx.z, lc = blockIdx.y, mb = blockIdx.x;
  const int m = mb * 256 + threadIdx.x;
  const float* s = scores + ((size_t)zn * L + lc * 256) * L + m;
  float mx = -3.0e38f, sum = 0.f;
  for (int i = 0; i < 256; ++i) {
    float v = s[(size_t)i * L];
    float nm = fmaxf(mx, v);
    sum = sum * __expf(mx - nm) + __expf(v - nm);
    mx = nm;
  }
  pstats[((size_t)(n0 + zn) * L + m) * 8 + lc] = make_float2(mx, sum);
}

__global__ __launch_bounds__(256) void stats_merge(const float2* __restrict__ pstats,
                                                   float2* __restrict__ stats,
                                                   int n0) {
  const int gn = n0 + blockIdx.z;
  const int m = blockIdx.x * 256 + threadIdx.x;
  const float2* p = &pstats[((size_t)gn * L + m) * 8];
  float gm = -3.0e38f;
#pragma unroll
  for (int j = 0; j < 8; ++j) gm = fmaxf(gm, p[j].x);
  float gs = 0.f;
#pragma unroll
  for (int j = 0; j < 8; ++j) gs += p[j].y * __expf(p[j].x - gm);
  stats[(size_t)gn * L + m] = make_float2(gm, 1.f / gs);
}

// ------------------------------------------------------- attn -> bf16
__global__ __launch_bounds__(256) void convert_attn(const float* __restrict__ scores,
                                                    const float2* __restrict__ stats,
                                                    u16* __restrict__ attn, int n0) {
  const int zn = blockIdx.z, l = blockIdx.y;
  const int m = (blockIdx.x * 256 + threadIdx.x) * 4;
  const float4 v = *(const float4*)&scores[((size_t)zn * L + l) * L + m];
  const float2* st = &stats[(size_t)(n0 + zn) * L + m];
  const float2 s0 = st[0], s1 = st[1], s2 = st[2], s3 = st[3];
  ushort4 h;
  h.x = f2bf(__expf(v.x - s0.x) * s0.y);
  h.y = f2bf(__expf(v.y - s1.x) * s1.y);
  h.z = f2bf(__expf(v.z - s2.x) * s2.y);
  h.w = f2bf(__expf(v.w - s3.x) * s3.y);
  *(ushort4*)&attn[((size_t)zn * L + l) * L + m] = h;
}

// ----------------------------------------------------------------- launch
extern "C" void kernel_launch(void* const* d_in, const int* in_sizes, int n_in,
                              void* d_out, int out_size, void* d_ws, size_t ws_size,
                              hipStream_t stream) {
  const float* x = (const float*)d_in[0];
  const float* Wq = (const float*)d_in[1];
  const float* Wk = (const float*)d_in[2];
  float* out = (float*)d_out;

  char* ws = (char*)d_ws;
  size_t off = 0;
  auto alloc = [&](size_t bytes) -> void* {
    void* p = ws + off;
    off = (off + bytes + 255) & ~(size_t)255;
    return p;
  };
  u16* Whi = (u16*)alloc((size_t)2 * A * C * 2);
  u16* Wlo = (u16*)alloc((size_t)2 * A * C * 2);
  u16* xh = (u16*)alloc((size_t)NL * C * 2);
  u16* xl = (u16*)alloc((size_t)NL * C * 2);
  u16* KQhi = (u16*)alloc((size_t)2 * NL * A * 2);
  u16* KQlo = (u16*)alloc((size_t)2 * NL * A * 2);
  u16* xT = (u16*)alloc((size_t)N * C * L * 2);
  float2* pstats = (float2*)alloc((size_t)N * L * 8 * 8);
  float2* stats = (float2*)alloc((size_t)N * L * 8);
  const size_t fixed = off;
  const size_t per_n = (size_t)L * L * 4 + (size_t)L * L * 2;  // scores + attn
  int chunk = 1;
  if (ws_size > fixed + per_n) {
    size_t avail = (ws_size - fixed) / per_n;
    chunk = avail >= 8 ? 8 : (int)avail;
  }
  float* scores = (float*)alloc((size_t)L * L * 4 * chunk);
  u16* attn = (u16*)alloc((size_t)L * L * 2 * chunk);

  split_w<<<dim3(A * C / 4 / 256), dim3(256), 0, stream>>>(Wk, Wq, Whi, Wlo);
  split_x<<<dim3(NL * C / 4 / 256), dim3(256), 0, stream>>>(x, xh, xl);
  transpose_x<<<dim3(L / 64, C / 64, N), dim3(256), 0, stream>>>(x, xT);
  gemm8<0><<<dim3(8, 128, 1), dim3(512), 0, stream>>>(
      xh, xl, Whi, Wlo, KQhi, KQlo, nullptr, 0);
  for (int n0 = 0; n0 < N; n0 += chunk) {
    int cn = (N - n0) < chunk ? (N - n0) : chunk;
    gemm8<1><<<dim3(8, 8, cn), dim3(512), 0, stream>>>(
        KQhi, KQlo, KQhi + (size_t)NL * A, KQlo + (size_t)NL * A,
        nullptr, nullptr, scores, n0);
    stats_partial<<<dim3(L / 256, 8, cn), dim3(256), 0, stream>>>(scores, pstats, n0);
    stats_merge<<<dim3(L / 256, 1, cn), dim3(256), 0, stream>>>(pstats, stats, n0);
    convert_attn<<<dim3(L / 1024, L, cn), dim3(256), 0, stream>>>(scores, stats, attn, n0);
    gemm8<2><<<dim3(4, 8, cn), dim3(512), 0, stream>>>(
        attn, nullptr, xT, nullptr, nullptr, nullptr, out, n0);
  }
}